// Round 1
// baseline (966.494 us; speedup 1.0000x reference)
//
#include <hip/hip_runtime.h>

// Problem constants (match reference.py)
#define NCLASS 100
#define DDIM   512
#define NROWS  131072

#define CSLICE  64                   // columns per block (one lane per column)
#define NSLICES (DDIM / CSLICE)      // 8
#define ROWSPB  1024                 // rows per block
#define NRCHUNK (NROWS / ROWSPB)     // 128
#define THREADS 256                  // 4 waves

__device__ __forceinline__ void gAtomicAddF(float* p, float v) {
#if defined(__AMDGCN__)
    unsafeAtomicAdd(p, v);           // native global_atomic_add_f32
#else
    atomicAdd(p, v);
#endif
}

// Kernel 1: per-class partial sums of x and x^2 over a (row-chunk, col-slice)
// tile, accumulated in LDS, flushed to global accumulators with atomics.
__global__ __launch_bounds__(THREADS) void icv_accum_kernel(
    const float* __restrict__ feat,     // [NROWS][DDIM]
    const int*   __restrict__ labels,   // [NROWS]
    float*       __restrict__ sums_g,   // [NCLASS][DDIM]
    float*       __restrict__ sq_g,     // [NCLASS]
    int*         __restrict__ cnt_g)    // [NCLASS]
{
    __shared__ float s_sum[NCLASS * CSLICE];   // 25.6 KB
    __shared__ float s_sq [NCLASS * CSLICE];   // 25.6 KB
    __shared__ int   s_cnt[NCLASS];            // 0.4 KB

    const int tid  = threadIdx.x;
    const int wave = tid >> 6;
    const int lane = tid & 63;
    const int cs   = blockIdx.x & (NSLICES - 1);   // column slice 0..7
    const int rc   = blockIdx.x >> 3;              // row chunk 0..127
    const int row0 = rc * ROWSPB;
    const int col  = (cs << 6) | lane;

    for (int i = tid; i < NCLASS * CSLICE; i += THREADS) { s_sum[i] = 0.f; s_sq[i] = 0.f; }
    for (int i = tid; i < NCLASS; i += THREADS) s_cnt[i] = 0;
    __syncthreads();

    // Each wave walks rows row0+wave, +4, ... ; lane l handles column col.
    #pragma unroll 4
    for (int r = row0 + wave; r < row0 + ROWSPB; r += 4) {
        const int lab = labels[r];
        const float x = feat[(size_t)r * DDIM + col];
        atomicAdd(&s_sum[lab * CSLICE + lane], x);       // ds_add_f32, stride-1 -> conflict-free
        atomicAdd(&s_sq [lab * CSLICE + lane], x * x);
        if (cs == 0 && lane == 0) atomicAdd(&s_cnt[lab], 1);
    }
    __syncthreads();

    // Flush per-class column sums (coalesced atomics, distinct addresses).
    for (int i = tid; i < NCLASS * CSLICE; i += THREADS) {
        const int c = i >> 6;
        const int j = i & 63;
        gAtomicAddF(&sums_g[c * DDIM + (cs << 6) + j], s_sum[i]);
    }
    // Flush sq: wave w reduces classes w, w+4, ... across its 64 lanes.
    for (int c = wave; c < NCLASS; c += (THREADS >> 6)) {
        float v = s_sq[c * CSLICE + lane];
        for (int off = 32; off > 0; off >>= 1) v += __shfl_xor(v, off, 64);
        if (lane == 0) gAtomicAddF(&sq_g[c], v);
    }
    if (cs == 0) {
        for (int c = tid; c < NCLASS; c += THREADS)
            atomicAdd(&cnt_g[c], s_cnt[c]);
    }
}

// Kernel 2: trace(cov_c) per class and valid-mean -> out[0].
__global__ __launch_bounds__(256) void icv_finalize_kernel(
    const float* __restrict__ sums_g,
    const float* __restrict__ sq_g,
    const int*   __restrict__ cnt_g,
    float*       __restrict__ out)
{
    __shared__ float s_trace[NCLASS];
    __shared__ float s_valid[NCLASS];

    const int tid  = threadIdx.x;
    const int wave = tid >> 6;
    const int lane = tid & 63;

    for (int c = wave; c < NCLASS; c += 4) {
        float acc = 0.f;
        #pragma unroll
        for (int k = 0; k < DDIM / 64; ++k) {
            const float v = sums_g[c * DDIM + k * 64 + lane];
            acc += v * v;                      // ||sum_c||^2 partial
        }
        for (int off = 32; off > 0; off >>= 1) acc += __shfl_xor(acc, off, 64);
        if (lane == 0) {
            const float n    = (float)cnt_g[c];
            const float safe = fmaxf(n, 1.f);
            // ssd = sq - n * ||mu||^2,  mu = sums/safe_n  ->  sq - n*acc/safe^2
            const float ssd   = sq_g[c] - n * (acc / (safe * safe));
            const float trace = ssd / fmaxf(n - 1.f, 1.f);
            const bool  valid = (n >= 2.f);
            s_trace[c] = valid ? trace : 0.f;
            s_valid[c] = valid ? 1.f : 0.f;
        }
    }
    __syncthreads();
    if (tid == 0) {
        float tot = 0.f, vc = 0.f;
        for (int c = 0; c < NCLASS; ++c) { tot += s_trace[c]; vc += s_valid[c]; }
        out[0] = (vc > 0.f) ? (tot / fmaxf(vc, 1.f)) : 0.f;
    }
}

extern "C" void kernel_launch(void* const* d_in, const int* in_sizes, int n_in,
                              void* d_out, int out_size, void* d_ws, size_t ws_size,
                              hipStream_t stream) {
    const float* feat   = (const float*)d_in[0];
    const int*   labels = (const int*)d_in[1];
    float* out = (float*)d_out;

    // Workspace layout: sums[NCLASS*DDIM] f32 | sq[NCLASS] f32 | cnt[NCLASS] i32
    float* sums_g = (float*)d_ws;
    float* sq_g   = sums_g + NCLASS * DDIM;
    int*   cnt_g  = (int*)(sq_g + NCLASS);
    const size_t accum_bytes = (size_t)(NCLASS * DDIM + 2 * NCLASS) * 4;

    hipMemsetAsync(d_ws, 0, accum_bytes, stream);

    const dim3 grid(NSLICES * NRCHUNK);   // 1024 blocks
    icv_accum_kernel<<<grid, THREADS, 0, stream>>>(feat, labels, sums_g, sq_g, cnt_g);
    icv_finalize_kernel<<<1, 256, 0, stream>>>(sums_g, sq_g, cnt_g, out);
}

// Round 2
// 741.699 us; speedup vs baseline: 1.3031x; 1.3031x over previous
//
#include <hip/hip_runtime.h>

// Problem constants (match reference.py)
#define NCLASS 100
#define DDIM   512
#define NROWS  131072

#define CSLICE  64                   // columns per block (one lane per column)
#define NSLICES (DDIM / CSLICE)      // 8
#define ROWSPB  1024                 // rows per block
#define NRCHUNK (NROWS / ROWSPB)     // 128
#define THREADS 512                  // 8 waves
#define NWAVES  8

__device__ __forceinline__ void gAtomicAddF(float* p, float v) {
#if defined(__AMDGCN__)
    unsafeAtomicAdd(p, v);           // native global_atomic_add_f32
#else
    atomicAdd(p, v);
#endif
}

// Kernel 1: per-class (sum, sumsq) over a (row-chunk, col-slice) tile.
// Classes are partitioned across the 8 waves (lab & 7 == wave) so every LDS
// accumulator slot is owned by exactly one wave -> plain ds_read/ds_write RMW,
// NO atomics. Same-wave DS ops are executed in order by HW, so back-to-back
// updates of the same class are hazard-free and the loop pipelines.
__global__ __launch_bounds__(THREADS) void icv_accum_kernel(
    const float* __restrict__ feat,     // [NROWS][DDIM]
    const int*   __restrict__ labels,   // [NROWS]
    float*       __restrict__ sums_g,   // [NCLASS][DDIM]
    float*       __restrict__ sq_g,     // [NCLASS]
    int*         __restrict__ cnt_g)    // [NCLASS]
{
    __shared__ float2 s_acc[NCLASS * CSLICE];   // (sum, sumsq) : 51.2 KB
    __shared__ int    s_cnt[NCLASS];

    const int tid  = threadIdx.x;
    const int wave = tid >> 6;
    const int lane = tid & 63;
    const int cs   = blockIdx.x & (NSLICES - 1);   // column slice 0..7
    const int rc   = blockIdx.x >> 3;              // row chunk 0..127
    const int row0 = rc * ROWSPB;
    const int col  = (cs << 6) | lane;

    for (int i = tid; i < NCLASS * CSLICE; i += THREADS) s_acc[i] = make_float2(0.f, 0.f);
    if (tid < NCLASS) s_cnt[tid] = 0;
    __syncthreads();

    const int4*  lab4  = (const int4*)(labels + row0);
    const float* fbase = feat + (size_t)row0 * DDIM + col;
    const bool   count = (cs == 0) && (lane == 0);

    // Depth-2 prefetched label scan, 4 rows per group.
    int4 la = lab4[0];
    int4 lb = lab4[1];
    for (int g = 0; g < ROWSPB / 4; ++g) {
        const int4 ln = (g + 2 < ROWSPB / 4) ? lab4[g + 2] : la;
        const int  r4 = g << 2;
        #pragma unroll
        for (int j = 0; j < 4; ++j) {
            const int lab = (j == 0) ? la.x : (j == 1) ? la.y : (j == 2) ? la.z : la.w;
            if ((lab & 7) != wave) continue;           // wave-uniform branch
            const float x = fbase[(size_t)(r4 + j) * DDIM];
            const int   a = (lab << 6) | lane;
            float2 v = s_acc[a];                       // ds_read_b64
            v.x += x;
            v.y = fmaf(x, x, v.y);
            s_acc[a] = v;                              // ds_write_b64
            if (count) s_cnt[lab]++;                   // wave-owned, in-order
        }
        la = lb; lb = ln;
    }
    __syncthreads();

    // Flush column sums (distinct addresses per block; ~128 colliders/addr total).
    for (int i = tid; i < NCLASS * CSLICE; i += THREADS) {
        const int c = i >> 6;
        const int l = i & 63;
        gAtomicAddF(&sums_g[c * DDIM + (cs << 6) + l], s_acc[i].x);
    }
    // Reduce sumsq across the 64 columns of this slice, one value per class.
    for (int c = wave; c < NCLASS; c += NWAVES) {
        float v = s_acc[(c << 6) | lane].y;
        for (int off = 32; off > 0; off >>= 1) v += __shfl_xor(v, off, 64);
        if (lane == 0) gAtomicAddF(&sq_g[c], v);
    }
    if (cs == 0) {
        for (int c = tid; c < NCLASS; c += THREADS)
            atomicAdd(&cnt_g[c], s_cnt[c]);
    }
}

// Kernel 2: trace(cov_c) per class and valid-mean -> out[0].
__global__ __launch_bounds__(256) void icv_finalize_kernel(
    const float* __restrict__ sums_g,
    const float* __restrict__ sq_g,
    const int*   __restrict__ cnt_g,
    float*       __restrict__ out)
{
    __shared__ float s_trace[NCLASS];
    __shared__ float s_valid[NCLASS];

    const int tid  = threadIdx.x;
    const int wave = tid >> 6;
    const int lane = tid & 63;

    for (int c = wave; c < NCLASS; c += 4) {
        float acc = 0.f;
        #pragma unroll
        for (int k = 0; k < DDIM / 64; ++k) {
            const float v = sums_g[c * DDIM + k * 64 + lane];
            acc += v * v;                      // ||sum_c||^2 partial
        }
        for (int off = 32; off > 0; off >>= 1) acc += __shfl_xor(acc, off, 64);
        if (lane == 0) {
            const float n    = (float)cnt_g[c];
            const float safe = fmaxf(n, 1.f);
            // ssd = sq - n * ||mu||^2 = sq - n * (||sums||^2 / safe^2)
            const float ssd   = sq_g[c] - n * (acc / (safe * safe));
            const float trace = ssd / fmaxf(n - 1.f, 1.f);
            const bool  valid = (n >= 2.f);
            s_trace[c] = valid ? trace : 0.f;
            s_valid[c] = valid ? 1.f : 0.f;
        }
    }
    __syncthreads();
    if (tid == 0) {
        float tot = 0.f, vc = 0.f;
        for (int c = 0; c < NCLASS; ++c) { tot += s_trace[c]; vc += s_valid[c]; }
        out[0] = (vc > 0.f) ? (tot / fmaxf(vc, 1.f)) : 0.f;
    }
}

extern "C" void kernel_launch(void* const* d_in, const int* in_sizes, int n_in,
                              void* d_out, int out_size, void* d_ws, size_t ws_size,
                              hipStream_t stream) {
    const float* feat   = (const float*)d_in[0];
    const int*   labels = (const int*)d_in[1];
    float* out = (float*)d_out;

    // Workspace layout: sums[NCLASS*DDIM] f32 | sq[NCLASS] f32 | cnt[NCLASS] i32
    float* sums_g = (float*)d_ws;
    float* sq_g   = sums_g + NCLASS * DDIM;
    int*   cnt_g  = (int*)(sq_g + NCLASS);
    const size_t accum_bytes = (size_t)(NCLASS * DDIM + 2 * NCLASS) * 4;

    hipMemsetAsync(d_ws, 0, accum_bytes, stream);

    const dim3 grid(NSLICES * NRCHUNK);   // 1024 blocks
    icv_accum_kernel<<<grid, THREADS, 0, stream>>>(feat, labels, sums_g, sq_g, cnt_g);
    icv_finalize_kernel<<<1, 256, 0, stream>>>(sums_g, sq_g, cnt_g, out);
}

// Round 3
// 315.526 us; speedup vs baseline: 3.0631x; 2.3507x over previous
//
#include <hip/hip_runtime.h>

// Problem constants (match reference.py)
#define NCLASS 100
#define DDIM   512
#define NROWS  131072

#define CHUNK   512                 // rows per block (== THREADS: 1 row/thread in sort)
#define NCHUNK  (NROWS / CHUNK)     // 256
#define NSLICE  2                   // column slices: 256 cols each (float4 per lane)
#define THREADS 512                 // 8 waves
#define NWAVES  8
#define NCOPY   2                   // accumulator splay (by chunk parity)

__device__ __forceinline__ void gAtomicAddF(float* p, float v) {
#if defined(__AMDGCN__)
    unsafeAtomicAdd(p, v);          // native global_atomic_add_f32, fire-and-forget
#else
    atomicAdd(p, v);
#endif
}

// Kernel 1: per-chunk counting sort by class, then register-accumulated
// per-class (sum[4 cols/lane], sumsq) with float4 loads and depth-2 prefetch.
// No LDS ops and no atomics in the streaming loop.
__global__ __launch_bounds__(THREADS, 4) void icv_accum_kernel(
    const float* __restrict__ feat,     // [NROWS][DDIM]
    const int*   __restrict__ labels,   // [NROWS]
    float*       __restrict__ sums_g,   // [NCOPY][NCLASS][DDIM]
    float*       __restrict__ sq_g,     // [NCOPY][NCLASS]
    int*         __restrict__ cnt_g)    // [NCLASS]
{
    __shared__ int s_cnt[NCLASS];
    __shared__ int s_off[NCLASS];
    __shared__ int s_pos[NCLASS];
    __shared__ int s_scan[128];
    __shared__ int s_rows[CHUNK];

    const int tid   = threadIdx.x;
    const int wave  = tid >> 6;
    const int lane  = tid & 63;
    const int slice = blockIdx.x & (NSLICE - 1);
    const int chunk = blockIdx.x >> 1;
    const int row0  = chunk * CHUNK;

    // ---- Phase A: counting sort of this chunk's 512 rows by class ----
    if (tid < NCLASS) s_cnt[tid] = 0;
    __syncthreads();
    const int mylab = labels[row0 + tid];          // coalesced, 1 row/thread
    atomicAdd(&s_cnt[mylab], 1);
    __syncthreads();

    // Exclusive prefix over 100 bins via 128-wide Hillis-Steele inclusive scan.
    if (tid < 128) s_scan[tid] = (tid < NCLASS) ? s_cnt[tid] : 0;
    __syncthreads();
    #pragma unroll
    for (int d = 1; d < 128; d <<= 1) {
        int v = 0;
        if (tid < 128) { v = s_scan[tid]; if (tid >= d) v += s_scan[tid - d]; }
        __syncthreads();
        if (tid < 128) s_scan[tid] = v;
        __syncthreads();
    }
    if (tid < NCLASS) {
        const int e = s_scan[tid] - s_cnt[tid];    // exclusive offset
        s_off[tid] = e;
        s_pos[tid] = e;
    }
    __syncthreads();
    {   // scatter: class-sorted row indices
        const int p = atomicAdd(&s_pos[mylab], 1);
        s_rows[p] = tid;
    }
    __syncthreads();

    // ---- Phase B: per-class register accumulation, classes owned by wave ----
    const float4* f4   = (const float4*)feat;                  // row stride 128
    const size_t  base = (size_t)row0 * 128 + slice * 64 + lane;
    float* sums_c = sums_g + (size_t)(chunk & (NCOPY - 1)) * (NCLASS * DDIM);
    float* sq_c   = sq_g + (chunk & (NCOPY - 1)) * NCLASS;

    for (int c = wave; c < NCLASS; c += NWAVES) {
        const int n = s_cnt[c];
        if (n == 0) continue;
        const int i0 = s_off[c];

        float4 acc = make_float4(0.f, 0.f, 0.f, 0.f);
        float  sq  = 0.f;

        // depth-2 software pipeline over this class's rows
        float4 x0 = f4[base + (size_t)s_rows[i0] * 128];
        float4 x1 = (n > 1) ? f4[base + (size_t)s_rows[i0 + 1] * 128] : x0;
        for (int i = 2; i < n; ++i) {
            const float4 xn = f4[base + (size_t)s_rows[i0 + i] * 128];
            acc.x += x0.x; acc.y += x0.y; acc.z += x0.z; acc.w += x0.w;
            sq = fmaf(x0.x, x0.x, fmaf(x0.y, x0.y, fmaf(x0.z, x0.z, fmaf(x0.w, x0.w, sq))));
            x0 = x1; x1 = xn;
        }
        acc.x += x0.x; acc.y += x0.y; acc.z += x0.z; acc.w += x0.w;
        sq = fmaf(x0.x, x0.x, fmaf(x0.y, x0.y, fmaf(x0.z, x0.z, fmaf(x0.w, x0.w, sq))));
        if (n > 1) {
            acc.x += x1.x; acc.y += x1.y; acc.z += x1.z; acc.w += x1.w;
            sq = fmaf(x1.x, x1.x, fmaf(x1.y, x1.y, fmaf(x1.z, x1.z, fmaf(x1.w, x1.w, sq))));
        }

        // flush: coalesced global atomics, one set per (class, block)
        float* dst = sums_c + c * DDIM + slice * 256 + lane * 4;
        gAtomicAddF(dst + 0, acc.x);
        gAtomicAddF(dst + 1, acc.y);
        gAtomicAddF(dst + 2, acc.z);
        gAtomicAddF(dst + 3, acc.w);
        for (int off = 32; off > 0; off >>= 1) sq += __shfl_xor(sq, off, 64);
        if (lane == 0) gAtomicAddF(&sq_c[c], sq);
    }

    if (slice == 0 && tid < NCLASS)
        atomicAdd(&cnt_g[tid], s_cnt[tid]);
}

// Kernel 2: trace(cov_c) per class and valid-mean -> out[0].
__global__ __launch_bounds__(512) void icv_finalize_kernel(
    const float* __restrict__ sums_g,   // [NCOPY][NCLASS][DDIM]
    const float* __restrict__ sq_g,     // [NCOPY][NCLASS]
    const int*   __restrict__ cnt_g,    // [NCLASS]
    float*       __restrict__ out)
{
    __shared__ float s_trace[NCLASS];
    __shared__ float s_valid[NCLASS];

    const int tid  = threadIdx.x;
    const int wave = tid >> 6;
    const int lane = tid & 63;

    for (int c = wave; c < NCLASS; c += 8) {
        float acc = 0.f;
        #pragma unroll
        for (int k = 0; k < DDIM / 64; ++k) {
            const int   j = c * DDIM + k * 64 + lane;
            const float v = sums_g[j] + sums_g[NCLASS * DDIM + j];
            acc += v * v;                      // ||sum_c||^2 partial
        }
        for (int off = 32; off > 0; off >>= 1) acc += __shfl_xor(acc, off, 64);
        if (lane == 0) {
            const float n    = (float)cnt_g[c];
            const float safe = fmaxf(n, 1.f);
            const float sq   = sq_g[c] + sq_g[NCLASS + c];
            // ssd = sq - n * ||mu||^2 = sq - n * (||sums||^2 / safe^2)
            const float ssd   = sq - n * (acc / (safe * safe));
            const float trace = ssd / fmaxf(n - 1.f, 1.f);
            const bool  valid = (n >= 2.f);
            s_trace[c] = valid ? trace : 0.f;
            s_valid[c] = valid ? 1.f : 0.f;
        }
    }
    __syncthreads();
    if (tid == 0) {
        float tot = 0.f, vc = 0.f;
        for (int c = 0; c < NCLASS; ++c) { tot += s_trace[c]; vc += s_valid[c]; }
        out[0] = (vc > 0.f) ? (tot / fmaxf(vc, 1.f)) : 0.f;
    }
}

extern "C" void kernel_launch(void* const* d_in, const int* in_sizes, int n_in,
                              void* d_out, int out_size, void* d_ws, size_t ws_size,
                              hipStream_t stream) {
    const float* feat   = (const float*)d_in[0];
    const int*   labels = (const int*)d_in[1];
    float* out = (float*)d_out;

    // Workspace: sums[NCOPY][NCLASS][DDIM] f32 | sq[NCOPY][NCLASS] f32 | cnt[NCLASS] i32
    float* sums_g = (float*)d_ws;
    float* sq_g   = sums_g + NCOPY * NCLASS * DDIM;
    int*   cnt_g  = (int*)(sq_g + NCOPY * NCLASS);
    const size_t accum_bytes = (size_t)(NCOPY * NCLASS * DDIM + NCOPY * NCLASS + NCLASS) * 4;

    hipMemsetAsync(d_ws, 0, accum_bytes, stream);

    const dim3 grid(NCHUNK * NSLICE);   // 512 blocks
    icv_accum_kernel<<<grid, THREADS, 0, stream>>>(feat, labels, sums_g, sq_g, cnt_g);
    icv_finalize_kernel<<<1, 512, 0, stream>>>(sums_g, sq_g, cnt_g, out);
}

// Round 4
// 80.410 us; speedup vs baseline: 12.0196x; 3.9240x over previous
//
#include <hip/hip_runtime.h>

// Problem constants (match reference.py)
#define NCLASS 100
#define DDIM   512
#define NROWS  131072

#define CHUNK   1024                // rows per chunk (== THREADS)
#define NCHUNK  (NROWS / CHUNK)     // 128
#define NSLICE  2                   // 256 cols per slice (64 lanes x float4)
#define THREADS 1024                // 16 waves
#define NWAVES  16

// Kernel 1: per-chunk counting sort by class; each wave owns a CONTIGUOUS
// class range so its rows are one contiguous segment of s_rows. Flat depth-4
// software-pipelined float4 stream with register accumulation; per-class
// flush = plain coalesced stores to per-chunk partial buffers. NO atomics,
// NO LDS ops in the hot loop (s_rows reads are uniform broadcasts).
__global__ __launch_bounds__(THREADS) void icv_accum_kernel(
    const float* __restrict__ feat,     // [NROWS][DDIM]
    const int*   __restrict__ labels,   // [NROWS]
    float*       __restrict__ sums_p,   // [NCHUNK][NCLASS][DDIM]
    float*       __restrict__ sq_p,     // [NCHUNK][NSLICE][NCLASS]
    int*         __restrict__ cnt_p)    // [NCHUNK][NCLASS]
{
    __shared__ int s_cnt[NCLASS];
    __shared__ int s_off[NCLASS + 1];
    __shared__ int s_pos[NCLASS];
    __shared__ int s_scan[128];
    __shared__ int s_rows[CHUNK];

    const int tid   = threadIdx.x;
    const int wave  = tid >> 6;
    const int lane  = tid & 63;
    const int slice = blockIdx.x & (NSLICE - 1);
    const int chunk = blockIdx.x >> 1;
    const int row0  = chunk * CHUNK;

    // ---- Phase A: counting sort of 1024 rows by class ----
    if (tid < NCLASS) s_cnt[tid] = 0;
    __syncthreads();
    const int mylab = labels[row0 + tid];              // coalesced
    atomicAdd(&s_cnt[mylab], 1);
    __syncthreads();

    // exclusive prefix over 100 bins (128-wide Hillis-Steele)
    if (tid < 128) s_scan[tid] = (tid < NCLASS) ? s_cnt[tid] : 0;
    __syncthreads();
    #pragma unroll
    for (int d = 1; d < 128; d <<= 1) {
        int v = 0;
        if (tid < 128) { v = s_scan[tid]; if (tid >= d) v += s_scan[tid - d]; }
        __syncthreads();
        if (tid < 128) s_scan[tid] = v;
        __syncthreads();
    }
    if (tid < NCLASS) {
        const int e = s_scan[tid] - s_cnt[tid];
        s_off[tid] = e;
        s_pos[tid] = e;
    }
    if (tid == NCLASS) s_off[NCLASS] = CHUNK;
    __syncthreads();
    {
        const int p = atomicAdd(&s_pos[mylab], 1);
        s_rows[p] = tid;                               // class-sorted row ids
    }
    if (slice == 0 && tid < NCLASS)
        cnt_p[chunk * NCLASS + tid] = s_cnt[tid];      // plain store
    __syncthreads();

    // ---- Phase B: flat stream over this wave's contiguous class range ----
    // wave w owns classes [lo, hi): 7 classes for w<4, else 6 (sums to 100)
    const int lo = wave * 6 + min(wave, 4);
    const int hi = lo + 6 + (wave < 4 ? 1 : 0);
    const int i0 = s_off[lo];
    const int i1 = s_off[hi];

    const float4* f4   = (const float4*)feat;          // row stride 128
    const size_t  base = (size_t)row0 * (DDIM / 4) + slice * 64 + lane;

    int    c    = lo;
    int    cend = s_off[c + 1];
    float4 acc  = make_float4(0.f, 0.f, 0.f, 0.f);
    float  sq   = 0.f;

#define LOADROW(idx) f4[base + (size_t)s_rows[(idx)] * (DDIM / 4)]

#define FLUSH() do {                                                          \
        float s_ = sq;                                                        \
        s_ += __shfl_xor(s_, 32, 64); s_ += __shfl_xor(s_, 16, 64);           \
        s_ += __shfl_xor(s_,  8, 64); s_ += __shfl_xor(s_,  4, 64);           \
        s_ += __shfl_xor(s_,  2, 64); s_ += __shfl_xor(s_,  1, 64);           \
        float4* dst_ = (float4*)(sums_p                                       \
            + ((size_t)(chunk * NCLASS + c) * DDIM) + slice * 256) + lane;    \
        *dst_ = acc;                                                          \
        if (lane == 0) sq_p[(chunk * NSLICE + slice) * NCLASS + c] = s_;      \
        acc = make_float4(0.f, 0.f, 0.f, 0.f); sq = 0.f;                      \
        ++c;                                                                  \
        cend = (c <= NCLASS - 1) ? s_off[c + 1] : (CHUNK + 1);                \
    } while (0)

#define STEP(K, RING) {                                                       \
        const int i_ = ib + (K);                                              \
        if (i_ < i1) {                                                        \
            while (i_ >= cend) FLUSH();                                       \
            const float4 x_ = RING;                                           \
            const int ip_ = i_ + 4;                                           \
            if (ip_ < i1) RING = LOADROW(ip_);                                \
            acc.x += x_.x; acc.y += x_.y; acc.z += x_.z; acc.w += x_.w;       \
            sq = fmaf(x_.x, x_.x, fmaf(x_.y, x_.y,                            \
                 fmaf(x_.z, x_.z, fmaf(x_.w, x_.w, sq))));                    \
        }                                                                     \
    }

    float4 ring0 = make_float4(0.f, 0.f, 0.f, 0.f);
    float4 ring1 = ring0, ring2 = ring0, ring3 = ring0;
    if (i0 + 0 < i1) ring0 = LOADROW(i0 + 0);
    if (i0 + 1 < i1) ring1 = LOADROW(i0 + 1);
    if (i0 + 2 < i1) ring2 = LOADROW(i0 + 2);
    if (i0 + 3 < i1) ring3 = LOADROW(i0 + 3);

    for (int ib = i0; ib < i1; ib += 4) {
        STEP(0, ring0)
        STEP(1, ring1)
        STEP(2, ring2)
        STEP(3, ring3)
    }
    while (c < hi) FLUSH();                            // tail: remaining/empty classes
#undef STEP
#undef FLUSH
#undef LOADROW
}

// Kernel 2: per-class reduction of partials -> {trace_masked, valid}.
__global__ __launch_bounds__(512) void icv_reduce_kernel(
    const float* __restrict__ sums_p,   // [NCHUNK][NCLASS][DDIM]
    const float* __restrict__ sq_p,     // [NCHUNK][NSLICE][NCLASS]
    const int*   __restrict__ cnt_p,    // [NCHUNK][NCLASS]
    float*       __restrict__ cls_out)  // [NCLASS][2]
{
    __shared__ float sred[512];
    const int c = blockIdx.x;
    const int t = threadIdx.x;

    // column sum over chunks (thread t owns column t)
    float s = 0.f;
    const float* p = sums_p + (size_t)c * DDIM + t;
    #pragma unroll 8
    for (int ch = 0; ch < NCHUNK; ++ch)
        s += p[(size_t)ch * (NCLASS * DDIM)];
    sred[t] = s * s;
    __syncthreads();
    for (int d = 256; d > 0; d >>= 1) { if (t < d) sred[t] += sred[t + d]; __syncthreads(); }
    const float norm2 = sred[0];                       // ||sum_c||^2
    __syncthreads();

    sred[t] = (t < NCHUNK * NSLICE) ? sq_p[t * NCLASS + c] : 0.f;
    __syncthreads();
    for (int d = 256; d > 0; d >>= 1) { if (t < d) sred[t] += sred[t + d]; __syncthreads(); }
    const float sqtot = sred[0];
    __syncthreads();

    sred[t] = (t < NCHUNK) ? (float)cnt_p[t * NCLASS + c] : 0.f;
    __syncthreads();
    for (int d = 256; d > 0; d >>= 1) { if (t < d) sred[t] += sred[t + d]; __syncthreads(); }
    const float n = sred[0];

    if (t == 0) {
        const float safe  = fmaxf(n, 1.f);
        const float ssd   = sqtot - norm2 / safe;      // sq - n*||sums/n||^2
        const float trace = ssd / fmaxf(n - 1.f, 1.f);
        const bool  valid = (n >= 2.f);
        cls_out[c * 2 + 0] = valid ? trace : 0.f;
        cls_out[c * 2 + 1] = valid ? 1.f : 0.f;
    }
}

// Kernel 3: final valid-mean over 100 classes.
__global__ __launch_bounds__(128) void icv_final_kernel(
    const float* __restrict__ cls_out, float* __restrict__ out)
{
    __shared__ float st[128], sv[128];
    const int t = threadIdx.x;
    st[t] = (t < NCLASS) ? cls_out[t * 2 + 0] : 0.f;
    sv[t] = (t < NCLASS) ? cls_out[t * 2 + 1] : 0.f;
    __syncthreads();
    for (int d = 64; d > 0; d >>= 1) {
        if (t < d) { st[t] += st[t + d]; sv[t] += sv[t + d]; }
        __syncthreads();
    }
    if (t == 0) out[0] = (sv[0] > 0.f) ? (st[0] / fmaxf(sv[0], 1.f)) : 0.f;
}

extern "C" void kernel_launch(void* const* d_in, const int* in_sizes, int n_in,
                              void* d_out, int out_size, void* d_ws, size_t ws_size,
                              hipStream_t stream) {
    const float* feat   = (const float*)d_in[0];
    const int*   labels = (const int*)d_in[1];
    float* out = (float*)d_out;

    // Workspace layout (all written unconditionally -> no memset needed):
    // sums_p[NCHUNK][NCLASS][DDIM] f32  (26.2 MB)
    // sq_p  [NCHUNK][NSLICE][NCLASS] f32 (102 KB)
    // cnt_p [NCHUNK][NCLASS] i32        (51 KB)
    // cls_out[NCLASS][2] f32
    float* sums_p  = (float*)d_ws;
    float* sq_p    = sums_p + (size_t)NCHUNK * NCLASS * DDIM;
    int*   cnt_p   = (int*)(sq_p + NCHUNK * NSLICE * NCLASS);
    float* cls_out = (float*)(cnt_p + NCHUNK * NCLASS);

    icv_accum_kernel<<<dim3(NCHUNK * NSLICE), THREADS, 0, stream>>>(
        feat, labels, sums_p, sq_p, cnt_p);
    icv_reduce_kernel<<<dim3(NCLASS), 512, 0, stream>>>(
        sums_p, sq_p, cnt_p, cls_out);
    icv_final_kernel<<<dim3(1), 128, 0, stream>>>(cls_out, out);
}